// Round 9
// baseline (184.117 us; speedup 1.0000x reference)
//
#include <hip/hip_runtime.h>

// Head attention: B=32, S=2048, E=64, H=64, fp32 in/out, NO causal mask.
// R9: barrier-free direct-L2 attention. R8 proved K/V are L2-resident after
// the XCD swizzle (FETCH 233->12 MB), so LDS staging + per-tile barriers are
// pure overhead: each wave now loads its K-slice / V-slice MFMA fragments
// straight from global (6 vmem/wave-tile), register-prefetched 1 tile ahead.
// No __syncthreads in the main loop. LDS = merge scratch only.
//  prep_w: W f32 -> f16 (Q pre-scaled 0.125*log2e).
//  proj:   grid 1024, W frags direct from L2, direct f16x4 Q/K stores,
//          V transposed via small LDS tile (1 barrier per block).
//  attn:   block = (b, 64 q-rows); 4 waves x 16-key slices; register P
//          (S^T C-layout == 16x16x16 PV A-layout); fixed-scale p=2^s;
//          cross-wave merge via LDS at the end.

#define BATCH 32
#define SEQ   2048
#define HS    64
#define QSCALE 0.18033688011112042f   // 0.125 * log2(e)
#define OTS   72                       // proj V-tile stride (144B)
#define OPAD  20                       // attn O-merge row pad (80B)

typedef _Float16 f16x8 __attribute__((ext_vector_type(8)));
typedef _Float16 f16x4 __attribute__((ext_vector_type(4)));
typedef float    f32x4 __attribute__((ext_vector_type(4)));

__global__ __launch_bounds__(256) void prep_w(
    const float* __restrict__ Wq, const float* __restrict__ Wk,
    const float* __restrict__ Wv, _Float16* __restrict__ Wh)
{
    int i = blockIdx.x * 256 + threadIdx.x;   // 0..12287
    const float* src = (i < 4096) ? Wq : ((i < 8192) ? Wk : Wv);
    float scale = (i < 4096) ? QSCALE : 1.0f;
    Wh[i] = (_Float16)(src[i & 4095] * scale);
}

__global__ __launch_bounds__(256) void proj_kernel(
    const float* __restrict__ x, const _Float16* __restrict__ Wh,
    _Float16* __restrict__ Qh, _Float16* __restrict__ Kh,
    _Float16* __restrict__ Vt)
{
    __shared__ __align__(16) _Float16 ot[64 * OTS];   // V transpose tile, 9KB

    const int t    = threadIdx.x;
    const int w    = t >> 6;
    const int lane = t & 63;
    const int lo   = lane & 15;
    const int quad = lane >> 4;
    const long blk0 = (long)blockIdx.x * 64;
    const int  b    = (int)(blk0 / SEQ);
    const int  s0   = (int)(blk0 % SEQ);
    const long rw   = blk0 + w * 16;

    // x B-fragment: B[k=e][n=srow=lo]
    const float* xp = x + (rw + lo) * HS + quad * 8;
    float4 x0 = *(const float4*)xp;
    float4 x1 = *(const float4*)(xp + 4);
    float4 x2 = *(const float4*)(xp + 32);
    float4 x3 = *(const float4*)(xp + 36);
    f16x8 xb0, xb1;
    xb0[0]=(_Float16)x0.x; xb0[1]=(_Float16)x0.y; xb0[2]=(_Float16)x0.z; xb0[3]=(_Float16)x0.w;
    xb0[4]=(_Float16)x1.x; xb0[5]=(_Float16)x1.y; xb0[6]=(_Float16)x1.z; xb0[7]=(_Float16)x1.w;
    xb1[0]=(_Float16)x2.x; xb1[1]=(_Float16)x2.y; xb1[2]=(_Float16)x2.z; xb1[3]=(_Float16)x2.w;
    xb1[4]=(_Float16)x3.x; xb1[5]=(_Float16)x3.y; xb1[6]=(_Float16)x3.z; xb1[7]=(_Float16)x3.w;

#pragma unroll
    for (int m = 0; m < 3; ++m) {
        const _Float16* Wm = Wh + m * 4096;
        f32x4 acc[4];
#pragma unroll
        for (int nt = 0; nt < 4; ++nt) { acc[nt][0]=0.f; acc[nt][1]=0.f; acc[nt][2]=0.f; acc[nt][3]=0.f; }
#pragma unroll
        for (int nt = 0; nt < 4; ++nt) {
            // W A-frag: A[m=h=16nt+lo][k=e=quad*8+j (+32)]
            f16x8 wa0 = *(const f16x8*)(Wm + (nt * 16 + lo) * 64 + quad * 8);
            f16x8 wa1 = *(const f16x8*)(Wm + (nt * 16 + lo) * 64 + 32 + quad * 8);
            acc[nt] = __builtin_amdgcn_mfma_f32_16x16x32_f16(wa0, xb0, acc[nt], 0, 0, 0);
            acc[nt] = __builtin_amdgcn_mfma_f32_16x16x32_f16(wa1, xb1, acc[nt], 0, 0, 0);
        }
        // D[m=h][n=srow]: lane holds srow=lo, h=16nt+4quad+r
        if (m < 2) {
            _Float16* dst = (m == 0) ? Qh : Kh;
#pragma unroll
            for (int nt = 0; nt < 4; ++nt) {
                f16x4 pk;
                pk[0]=(_Float16)acc[nt][0]; pk[1]=(_Float16)acc[nt][1];
                pk[2]=(_Float16)acc[nt][2]; pk[3]=(_Float16)acc[nt][3];
                *(f16x4*)(dst + (rw + lo) * HS + nt * 16 + quad * 4) = pk;
            }
        } else {
            // V transposed: ot[h][srow]
#pragma unroll
            for (int nt = 0; nt < 4; ++nt)
#pragma unroll
                for (int r = 0; r < 4; ++r)
                    ot[(nt * 16 + quad * 4 + r) * OTS + w * 16 + lo] = (_Float16)acc[nt][r];
            __syncthreads();
            const int row = t >> 2, c = t & 3;
            f16x8 r0 = *(const f16x8*)(ot + row * OTS + c * 16);
            f16x8 r1 = *(const f16x8*)(ot + row * OTS + c * 16 + 8);
            _Float16* vd = Vt + ((long)b * HS + row) * SEQ + s0 + c * 16;
            *(f16x8*)vd       = r0;
            *(f16x8*)(vd + 8) = r1;
        }
    }
}

__global__ __launch_bounds__(256) void attn_kernel(
    const _Float16* __restrict__ Q, const _Float16* __restrict__ K,
    const _Float16* __restrict__ Vt, float* __restrict__ out)
{
    __shared__ float obuf[4][64][OPAD];   // O-merge scratch, 20 KB
    __shared__ float lsm[4][64];          // l partials, 1 KB

    const int t    = threadIdx.x;
    const int w    = t >> 6;
    const int lane = t & 63;
    const int lo   = lane & 15;
    const int quad = lane >> 4;

    // XCD-affinity swizzle: one batch's 32 q-blocks share bid%8 (one XCD)
    const int bid = blockIdx.x;
    const int b   = (bid & 7) | ((bid >> 8) << 3);
    const int qt  = (bid >> 3) & 31;
    const int q0  = qt * 64;

    // Q B-fragments for 4 q-tiles: B[k=h][n=q=lo]
    const _Float16* Qb = Q + ((long)b * SEQ + q0) * HS;
    f16x8 qf[4][2];
#pragma unroll
    for (int nt = 0; nt < 4; ++nt) {
        qf[nt][0] = *(const f16x8*)(Qb + (nt * 16 + lo) * HS + quad * 8);
        qf[nt][1] = *(const f16x8*)(Qb + (nt * 16 + lo) * HS + 32 + quad * 8);
    }

    const int keyw = w * 16;   // this wave's key slice within each tile
    // lane-invariant bases
    const _Float16* kbase = K  + (long)b * SEQ * HS + (long)(keyw + lo) * HS + quad * 8;
    const _Float16* vbase = Vt + (long)b * HS * SEQ + (long)lo * SEQ + keyw + quad * 4;

    f32x4 o[4][4];
    float l_lane[4] = {0.f, 0.f, 0.f, 0.f};
#pragma unroll
    for (int nt = 0; nt < 4; ++nt)
#pragma unroll
        for (int ht = 0; ht < 4; ++ht) { o[nt][ht][0]=0.f; o[nt][ht][1]=0.f; o[nt][ht][2]=0.f; o[nt][ht][3]=0.f; }

    f32x4 zz; zz[0]=0.f; zz[1]=0.f; zz[2]=0.f; zz[3]=0.f;

    // prefetch tile 0 fragments (phase-offset start: tile (qt&31))
    int key0 = (qt & 31) << 6;
    f16x8 ka0 = *(const f16x8*)(kbase + (long)key0 * HS);
    f16x8 ka1 = *(const f16x8*)(kbase + (long)key0 * HS + 32);
    f16x4 vbf[4];
#pragma unroll
    for (int ht = 0; ht < 4; ++ht)
        vbf[ht] = *(const f16x4*)(vbase + (long)ht * 16 * SEQ + key0);

    for (int kt = 0; kt < 32; ++kt) {
        // prefetch next tile (wraps on last iter; values unused)
        const int keyn = ((kt + 1 + qt) & 31) << 6;
        f16x8 kn0 = *(const f16x8*)(kbase + (long)keyn * HS);
        f16x8 kn1 = *(const f16x8*)(kbase + (long)keyn * HS + 32);
        f16x4 vn[4];
#pragma unroll
        for (int ht = 0; ht < 4; ++ht)
            vn[ht] = *(const f16x4*)(vbase + (long)ht * 16 * SEQ + keyn);

        // S^T = K_slice . Q^T; lane: q=nt*16+lo, key=keyw+quad*4+r
#pragma unroll
        for (int nt = 0; nt < 4; ++nt) {
            f32x4 s;
            s = __builtin_amdgcn_mfma_f32_16x16x32_f16(ka0, qf[nt][0], zz, 0, 0, 0);
            s = __builtin_amdgcn_mfma_f32_16x16x32_f16(ka1, qf[nt][1], s,  0, 0, 0);

            // fixed-scale softmax p=2^s (associative across waves/tiles)
            float p0 = exp2f(s[0]);
            float p1 = exp2f(s[1]);
            float p2 = exp2f(s[2]);
            float p3 = exp2f(s[3]);
            l_lane[nt] += (p0 + p1) + (p2 + p3);
            f16x4 pa;
            pa[0]=(_Float16)p0; pa[1]=(_Float16)p1; pa[2]=(_Float16)p2; pa[3]=(_Float16)p3;
            // pa IS the 16x16x16 A-frag: A[m=q=lo][k=key=quad*4+j]
#pragma unroll
            for (int ht = 0; ht < 4; ++ht)
                o[nt][ht] = __builtin_amdgcn_mfma_f32_16x16x16f16(pa, vbf[ht], o[nt][ht], 0, 0, 0);
        }

        ka0 = kn0; ka1 = kn1;
#pragma unroll
        for (int ht = 0; ht < 4; ++ht) vbf[ht] = vn[ht];
    }

    // ---- cross-wave merge ----
#pragma unroll
    for (int nt = 0; nt < 4; ++nt) {
        float lq = l_lane[nt];
        lq += __shfl_xor(lq, 16);
        lq += __shfl_xor(lq, 32);
        if (quad == 0) lsm[w][nt * 16 + lo] = lq;
    }

    const int ql = w * 16 + (lane >> 2);
    const int hc = lane & 3;
    float inv = 0.f;

    for (int ht = 0; ht < 4; ++ht) {
#pragma unroll
        for (int nt = 0; nt < 4; ++nt)
#pragma unroll
            for (int r = 0; r < 4; ++r)
                obuf[w][nt * 16 + quad * 4 + r][lo] = o[nt][ht][r];
        __syncthreads();
        if (ht == 0)
            inv = 1.0f / (lsm[0][ql] + lsm[1][ql] + lsm[2][ql] + lsm[3][ql]);
        f32x4 sum = *(const f32x4*)&obuf[0][ql][hc * 4];
        sum = sum + *(const f32x4*)&obuf[1][ql][hc * 4];
        sum = sum + *(const f32x4*)&obuf[2][ql][hc * 4];
        sum = sum + *(const f32x4*)&obuf[3][ql][hc * 4];
        sum = sum * inv;
        *(f32x4*)(out + ((long)b * SEQ + q0 + ql) * HS + ht * 16 + hc * 4) = sum;
        __syncthreads();   // obuf free for next ht
    }
}

extern "C" void kernel_launch(void* const* d_in, const int* in_sizes, int n_in,
                              void* d_out, int out_size, void* d_ws, size_t ws_size,
                              hipStream_t stream)
{
    const float* x  = (const float*)d_in[0];
    const float* Wq = (const float*)d_in[1];
    const float* Wk = (const float*)d_in[2];
    const float* Wv = (const float*)d_in[3];
    float* out = (float*)d_out;

    const size_t E = (size_t)BATCH * SEQ * HS;   // 4,194,304
    _Float16* Qh = (_Float16*)d_ws;
    _Float16* Kh = Qh + E;
    _Float16* Vt = Kh + E;
    _Float16* Wh = Vt + E;    // 3*4096 f16; ws total ~25.2 MB

    prep_w<<<48, 256, 0, stream>>>(Wq, Wk, Wv, Wh);
    proj_kernel<<<(BATCH * SEQ) / 64, 256, 0, stream>>>(x, Wh, Qh, Kh, Vt);
    attn_kernel<<<BATCH * (SEQ / 64), 256, 0, stream>>>(Qh, Kh, Vt, out);
}

// Round 11
// 143.911 us; speedup vs baseline: 1.2794x; 1.2794x over previous
//
#include <hip/hip_runtime.h>

// Head attention: B=32, S=2048, E=64, H=64, fp32 in/out, NO causal mask.
// R11: proven 3-kernel skeleton + verified attn upgrades from R10's design:
//  - K staged in PERMUTED row order (LDS row = (k&32)|((k>>2)&1)*16|
//    ((k>>3)&3)*4|(k&3)) so the S^T C-layout IS the 16x16x32 PV A-fragment:
//    waves own 32-key halves, PV runs K=32 -> 16 QK/PV MFMA + 2 l-MFMA
//    per wave-tile (was 24), 8 b128 LDS reads.
//  - raw v_exp_f32 via __builtin_amdgcn_exp2f (fixed-scale p=2^s, associative).
//  - l computed by MFMA vs all-ones B-frag (no per-tile adds/shfl; l and O
//    both from the same f16 P).
//  - proj: R9 structure + 8x-replicated f16 W (rep = bid&7) to kill the
//    L2 hot-line serialization; XCD-affinity swizzle in attn kept.

#define BATCH 32
#define SEQ   2048
#define HS    64
#define QSCALE 0.18033688011112042f   // 0.125 * log2(e)
#define OTS   72                       // proj V-transpose row stride (halves)
#define OPAD  20                       // merge row pad (floats)

typedef _Float16 f16x8 __attribute__((ext_vector_type(8)));
typedef _Float16 f16x4 __attribute__((ext_vector_type(4)));
typedef float    f32x4 __attribute__((ext_vector_type(4)));

__global__ __launch_bounds__(256) void prep_w(
    const float* __restrict__ Wq, const float* __restrict__ Wk,
    const float* __restrict__ Wv, _Float16* __restrict__ Wh)
{
    int i = blockIdx.x * 256 + threadIdx.x;   // 0..98303 (8 replicas x 12288)
    int rep = i / 12288;
    int j = i - rep * 12288;
    const float* src = (j < 4096) ? Wq : ((j < 8192) ? Wk : Wv);
    float scale = (j < 4096) ? QSCALE : 1.0f;
    Wh[i] = (_Float16)(src[j & 4095] * scale);
}

__global__ __launch_bounds__(256) void proj_kernel(
    const float* __restrict__ x, const _Float16* __restrict__ Wh,
    _Float16* __restrict__ Qh, _Float16* __restrict__ Kh,
    _Float16* __restrict__ Vt)
{
    __shared__ __align__(16) _Float16 ot[64 * OTS];   // V transpose tile, 9KB

    const int t    = threadIdx.x;
    const int w    = t >> 6;
    const int lane = t & 63;
    const int lo   = lane & 15;
    const int quad = lane >> 4;
    const long blk0 = (long)blockIdx.x * 64;
    const int  b    = (int)(blk0 / SEQ);
    const int  s0   = (int)(blk0 % SEQ);
    const long rw   = blk0 + w * 16;
    const _Float16* Wrep = Wh + (blockIdx.x & 7) * 12288;  // 8x replicated W

    // x B-fragment: B[k=e][n=srow=lo]
    const float* xp = x + (rw + lo) * HS + quad * 8;
    float4 x0 = *(const float4*)xp;
    float4 x1 = *(const float4*)(xp + 4);
    float4 x2 = *(const float4*)(xp + 32);
    float4 x3 = *(const float4*)(xp + 36);
    f16x8 xb0, xb1;
    xb0[0]=(_Float16)x0.x; xb0[1]=(_Float16)x0.y; xb0[2]=(_Float16)x0.z; xb0[3]=(_Float16)x0.w;
    xb0[4]=(_Float16)x1.x; xb0[5]=(_Float16)x1.y; xb0[6]=(_Float16)x1.z; xb0[7]=(_Float16)x1.w;
    xb1[0]=(_Float16)x2.x; xb1[1]=(_Float16)x2.y; xb1[2]=(_Float16)x2.z; xb1[3]=(_Float16)x2.w;
    xb1[4]=(_Float16)x3.x; xb1[5]=(_Float16)x3.y; xb1[6]=(_Float16)x3.z; xb1[7]=(_Float16)x3.w;

#pragma unroll
    for (int m = 0; m < 3; ++m) {
        const _Float16* Wm = Wrep + m * 4096;
        f32x4 acc[4];
#pragma unroll
        for (int nt = 0; nt < 4; ++nt) { acc[nt][0]=0.f; acc[nt][1]=0.f; acc[nt][2]=0.f; acc[nt][3]=0.f; }
#pragma unroll
        for (int nt = 0; nt < 4; ++nt) {
            // W A-frag: A[m=h=16nt+lo][k=e=quad*8+j (+32)]
            f16x8 wa0 = *(const f16x8*)(Wm + (nt * 16 + lo) * 64 + quad * 8);
            f16x8 wa1 = *(const f16x8*)(Wm + (nt * 16 + lo) * 64 + 32 + quad * 8);
            acc[nt] = __builtin_amdgcn_mfma_f32_16x16x32_f16(wa0, xb0, acc[nt], 0, 0, 0);
            acc[nt] = __builtin_amdgcn_mfma_f32_16x16x32_f16(wa1, xb1, acc[nt], 0, 0, 0);
        }
        // D[m=h][n=srow]: lane holds srow=lo, h=16nt+4quad+r
        if (m < 2) {
            _Float16* dst = (m == 0) ? Qh : Kh;
#pragma unroll
            for (int nt = 0; nt < 4; ++nt) {
                f16x4 pk;
                pk[0]=(_Float16)acc[nt][0]; pk[1]=(_Float16)acc[nt][1];
                pk[2]=(_Float16)acc[nt][2]; pk[3]=(_Float16)acc[nt][3];
                *(f16x4*)(dst + (rw + lo) * HS + nt * 16 + quad * 4) = pk;
            }
        } else {
            // V transposed: ot[h][srow]
#pragma unroll
            for (int nt = 0; nt < 4; ++nt)
#pragma unroll
                for (int r = 0; r < 4; ++r)
                    ot[(nt * 16 + quad * 4 + r) * OTS + w * 16 + lo] = (_Float16)acc[nt][r];
            __syncthreads();
            const int row = t >> 2, c = t & 3;
            f16x8 r0 = *(const f16x8*)(ot + row * OTS + c * 16);
            f16x8 r1 = *(const f16x8*)(ot + row * OTS + c * 16 + 8);
            _Float16* vd = Vt + ((long)b * HS + row) * SEQ + s0 + c * 16;
            *(f16x8*)vd       = r0;
            *(f16x8*)(vd + 8) = r1;
        }
    }
}

__global__ __launch_bounds__(256) void attn_kernel(
    const _Float16* __restrict__ Q, const _Float16* __restrict__ K,
    const _Float16* __restrict__ Vt, float* __restrict__ out)
{
    // ping-pong tiles: buf = [K: 4096 halves | V: 4096 halves]; merge aliases
    __shared__ __align__(16) _Float16 KV[2][8192];   // 32 KB

    const int t    = threadIdx.x;
    const int w    = t >> 6;
    const int lane = t & 63;
    const int lo   = lane & 15;
    const int quad = lane >> 4;
    const int sr   = t >> 2, sc = t & 3;
    const int xr   = lo & 7;

    // XCD-affinity swizzle: one batch's 32 q-blocks share bid%8 (one XCD)
    const int bid = blockIdx.x;
    const int b   = (bid & 7) | ((bid >> 8) << 3);
    const int qt  = (bid >> 3) & 31;
    const int q0  = qt * 64;
    const int qh  = w >> 1;    // q half (32 rows)
    const int kh  = w & 1;     // key half (32 keys)

    // Q B-fragments for this wave's 2 q-tiles: B[k=h][n=q=lo]
    const _Float16* Qb = Q + ((long)b * SEQ + q0 + qh * 32) * HS;
    f16x8 qf[2][2];
#pragma unroll
    for (int q2 = 0; q2 < 2; ++q2) {
        qf[q2][0] = *(const f16x8*)(Qb + (q2 * 16 + lo) * HS + quad * 8);
        qf[q2][1] = *(const f16x8*)(Qb + (q2 * 16 + lo) * HS + 32 + quad * 8);
    }

    const _Float16* Kb = K  + (long)b * SEQ * HS;
    const _Float16* Vb = Vt + (long)b * HS * SEQ;

    // K staged in permuted row order: physical key k -> LDS row
    //   (k&32) | ((k>>2)&1)*16 | ((k>>3)&3)*4 | (k&3)
    const int pr  = (sr & 32) | ((sr & 4) << 2) | ((sr & 24) >> 1) | (sr & 3);
    const int kw0 = pr * 64 + (((2 * sc    ) ^ (pr & 7)) << 3);
    const int kw1 = pr * 64 + (((2 * sc + 1) ^ (pr & 7)) << 3);
    const int vw0 = 4096 + sr * 64 + (((2 * sc    ) ^ (sr & 7)) << 3);
    const int vw1 = 4096 + sr * 64 + (((2 * sc + 1) ^ (sr & 7)) << 3);

    const int kr0 = (kh * 32      + lo) * 64;
    const int kr1 = (kh * 32 + 16 + lo) * 64;
    const int g0  = ((quad    ) ^ xr) << 3;
    const int g1  = ((4 + quad) ^ xr) << 3;
    int voff[4];
#pragma unroll
    for (int ht = 0; ht < 4; ++ht)
        voff[ht] = 4096 + (ht * 16 + lo) * 64 + (((kh * 4 + quad) ^ xr) << 3);

    f32x4 o[2][4], ol[2];
#pragma unroll
    for (int q2 = 0; q2 < 2; ++q2) {
        ol[q2][0]=0.f; ol[q2][1]=0.f; ol[q2][2]=0.f; ol[q2][3]=0.f;
#pragma unroll
        for (int ht = 0; ht < 4; ++ht) { o[q2][ht][0]=0.f; o[q2][ht][1]=0.f; o[q2][ht][2]=0.f; o[q2][ht][3]=0.f; }
    }
    f32x4 zz; zz[0]=0.f; zz[1]=0.f; zz[2]=0.f; zz[3]=0.f;
    f16x8 ones;
#pragma unroll
    for (int j = 0; j < 8; ++j) ones[j] = (_Float16)1.0f;

    // prefetch tile 0 (phase-offset start)
    const int key0 = (qt & 31) << 6;
    f16x8 kfA = *(const f16x8*)(Kb + (long)(key0 + sr) * HS + sc * 16);
    f16x8 kfB = *(const f16x8*)(Kb + (long)(key0 + sr) * HS + sc * 16 + 8);
    f16x8 vfA = *(const f16x8*)(Vb + (long)sr * SEQ + key0 + sc * 16);
    f16x8 vfB = *(const f16x8*)(Vb + (long)sr * SEQ + key0 + sc * 16 + 8);

    for (int kt = 0; kt < 32; ++kt) {
        _Float16* Ksp = &KV[kt & 1][0];
        *(f16x8*)(Ksp + kw0) = kfA;
        *(f16x8*)(Ksp + kw1) = kfB;
        *(f16x8*)(Ksp + vw0) = vfA;
        *(f16x8*)(Ksp + vw1) = vfB;

        // prefetch next tile (wraps; values unused on last iter)
        const int keyn = ((kt + 1 + qt) & 31) << 6;
        kfA = *(const f16x8*)(Kb + (long)(keyn + sr) * HS + sc * 16);
        kfB = *(const f16x8*)(Kb + (long)(keyn + sr) * HS + sc * 16 + 8);
        vfA = *(const f16x8*)(Vb + (long)sr * SEQ + keyn + sc * 16);
        vfB = *(const f16x8*)(Vb + (long)sr * SEQ + keyn + sc * 16 + 8);

        __syncthreads();   // tile staged (ping-pong: single barrier/tile)

        // K A-frags: permuted rows give key = kh*32 + quad*8 + (0..3|4..7)
        f16x8 ka00 = *(const f16x8*)(Ksp + kr0 + g0);
        f16x8 ka01 = *(const f16x8*)(Ksp + kr0 + g1);
        f16x8 ka10 = *(const f16x8*)(Ksp + kr1 + g0);
        f16x8 ka11 = *(const f16x8*)(Ksp + kr1 + g1);

        // V B-frags (16x16x32): B[k=key=kh*32+quad*8+j][n=h=lo]
        f16x8 vbf[4];
#pragma unroll
        for (int ht = 0; ht < 4; ++ht)
            vbf[ht] = *(const f16x8*)(Ksp + voff[ht]);

#pragma unroll
        for (int q2 = 0; q2 < 2; ++q2) {
            f32x4 s0, s1;
            s0 = __builtin_amdgcn_mfma_f32_16x16x32_f16(ka00, qf[q2][0], zz, 0, 0, 0);
            s0 = __builtin_amdgcn_mfma_f32_16x16x32_f16(ka01, qf[q2][1], s0, 0, 0, 0);
            s1 = __builtin_amdgcn_mfma_f32_16x16x32_f16(ka10, qf[q2][0], zz, 0, 0, 0);
            s1 = __builtin_amdgcn_mfma_f32_16x16x32_f16(ka11, qf[q2][1], s1, 0, 0, 0);

            // fixed-scale softmax p = 2^s (raw v_exp_f32)
            float e0 = __builtin_amdgcn_exp2f(s0[0]);
            float e1 = __builtin_amdgcn_exp2f(s0[1]);
            float e2 = __builtin_amdgcn_exp2f(s0[2]);
            float e3 = __builtin_amdgcn_exp2f(s0[3]);
            float e4 = __builtin_amdgcn_exp2f(s1[0]);
            float e5 = __builtin_amdgcn_exp2f(s1[1]);
            float e6 = __builtin_amdgcn_exp2f(s1[2]);
            float e7 = __builtin_amdgcn_exp2f(s1[3]);

            f16x8 pa;   // A[m=q=lo][k=key=quad*8+j]
            pa[0]=(_Float16)e0; pa[1]=(_Float16)e1; pa[2]=(_Float16)e2; pa[3]=(_Float16)e3;
            pa[4]=(_Float16)e4; pa[5]=(_Float16)e5; pa[6]=(_Float16)e6; pa[7]=(_Float16)e7;

            // l by MFMA: D[q][*] = sum_k P[q][k] (same f16 P as O)
            ol[q2] = __builtin_amdgcn_mfma_f32_16x16x32_f16(pa, ones, ol[q2], 0, 0, 0);
#pragma unroll
            for (int ht = 0; ht < 4; ++ht)
                o[q2][ht] = __builtin_amdgcn_mfma_f32_16x16x32_f16(pa, vbf[ht], o[q2][ht], 0, 0, 0);
        }
    }

    // ---- merge (2-way across key-half waves), aliasing KV ----
    __syncthreads();
    float* obuf = (float*)&KV[0][0];        // [4*32][OPAD] = 10240 B
    float* lsm  = obuf + 4 * 32 * OPAD;     // [4*32] = 512 B

    // ol[q2][r] = l[q=qh*32+q2*16+quad*4+r] (identical across lo)
    if (lo == 0) {
#pragma unroll
        for (int q2 = 0; q2 < 2; ++q2)
#pragma unroll
            for (int r = 0; r < 4; ++r)
                lsm[w * 32 + q2 * 16 + quad * 4 + r] = ol[q2][r];
    }

    const int ql = w * 16 + (lane >> 2);   // q-row this lane finalizes (0..63)
    const int hc = lane & 3;
    const int ra = (2 * (ql >> 5)) * 32 + (ql & 31);       // kh=0 partial
    const int rb = (2 * (ql >> 5) + 1) * 32 + (ql & 31);   // kh=1 partial
    float inv = 0.f;

    for (int ht = 0; ht < 4; ++ht) {
#pragma unroll
        for (int q2 = 0; q2 < 2; ++q2)
#pragma unroll
            for (int r = 0; r < 4; ++r)
                obuf[(w * 32 + q2 * 16 + quad * 4 + r) * OPAD + lo] = o[q2][ht][r];
        __syncthreads();
        if (ht == 0) inv = 1.0f / (lsm[ra] + lsm[rb]);
        f32x4 sum = *(const f32x4*)&obuf[ra * OPAD + hc * 4];
        sum = sum + *(const f32x4*)&obuf[rb * OPAD + hc * 4];
        sum = sum * inv;
        *(f32x4*)(out + ((long)b * SEQ + q0 + ql) * HS + ht * 16 + hc * 4) = sum;
        __syncthreads();   // obuf free for next ht
    }
}

extern "C" void kernel_launch(void* const* d_in, const int* in_sizes, int n_in,
                              void* d_out, int out_size, void* d_ws, size_t ws_size,
                              hipStream_t stream)
{
    const float* x  = (const float*)d_in[0];
    const float* Wq = (const float*)d_in[1];
    const float* Wk = (const float*)d_in[2];
    const float* Wv = (const float*)d_in[3];
    float* out = (float*)d_out;

    const size_t E = (size_t)BATCH * SEQ * HS;   // 4,194,304
    _Float16* Qh = (_Float16*)d_ws;
    _Float16* Kh = Qh + E;
    _Float16* Vt = Kh + E;
    _Float16* Wh = Vt + E;    // 8 replicas x 12288 halves; ws ~25.4 MB

    prep_w<<<384, 256, 0, stream>>>(Wq, Wk, Wv, Wh);
    proj_kernel<<<(BATCH * SEQ) / 64, 256, 0, stream>>>(x, Wh, Qh, Kh, Vt);
    attn_kernel<<<BATCH * (SEQ / 64), 256, 0, stream>>>(Qh, Kh, Vt, out);
}